// Round 3
// baseline (168.929 us; speedup 1.0000x reference)
//
#include <hip/hip_runtime.h>

// Problem constants: x [B=1,T=8,C=32,D=32,H=64,W=64] fp32
constexpr int NT = 8;    // B*T
constexpr int C  = 32;
constexpr int D  = 32;
constexpr int H  = 64;
constexpr int W  = 64;   // == wavefront size: W-conv via lane shuffles
constexpr int SP = D * H * W;           // 131072
constexpr int LDS_BYTES = C * (D / 2) * W * 4;   // h packed 2xbf16: 131072 B

// bf16 helpers (RNE pack, cheap unpack)
static __device__ __forceinline__ unsigned f2bf(float f) {
    unsigned u = __float_as_uint(f);
    return (u + 0x7fffu + ((u >> 16) & 1u)) >> 16;
}
static __device__ __forceinline__ float bf_lo(unsigned v) { return __uint_as_float(v << 16); }
static __device__ __forceinline__ float bf_hi(unsigned v) { return __uint_as_float(v & 0xffff0000u); }

// ---------------------------------------------------------------------------
// Fully fused LSKA block:
//   dw chain (z3, x3, y3, 3x z5-dil2)  ->  bf16 LDS  ->  1x1x1 pw conv
//   -> residual multiply -> out.
// Block = (n, hg): 1024 threads.
//   Phase A: thread (cp = tid>>6, w = tid&63) computes dw chain for channels
//            cp and cp+16; each owns the full D=32 column in registers.
//            H-neighbors from global (L2-local via XCD swizzle), W via shfl.
//   Phase B: thread (dp = tid>>6, w) owns d = {2dp, 2dp+1}: reads all 32
//            channels from LDS (each element read once), 32x32 mix in fp32,
//            residual x re-read (L3-warm), store.
// Bias boundary semantics: when a later conv's tap falls outside the image,
// that whole term (incl. earlier biases) drops — the skip logic below.
// ---------------------------------------------------------------------------
__global__ __launch_bounds__(1024, 4)
void lska_fused(const float* __restrict__ x,
                const float* __restrict__ w0z, const float* __restrict__ b0z,
                const float* __restrict__ w0x, const float* __restrict__ b0x,
                const float* __restrict__ w0y, const float* __restrict__ b0y,
                const float* __restrict__ wsz, const float* __restrict__ bsz,
                const float* __restrict__ wp,  const float* __restrict__ bp,
                float* __restrict__ out)
{
    extern __shared__ unsigned smem[];   // [C][D/2][W] packed 2xbf16

    // XCD-chunk swizzle: 512 blocks, 8 XCDs -> XCD k gets logical ids
    // [k*64,(k+1)*64) = one full n with consecutive hg (L2 halo locality).
    const int rr  = blockIdx.x;
    const int lid = (rr & 7) * (NT * H / 8) + (rr >> 3);
    const int n   = lid >> 6;
    const int hg  = lid & 63;

    const int tid = threadIdx.x;
    const int w   = tid & 63;

    // ---------------- Phase A: depthwise chain, 2 channels/thread ----------
    const int cp = tid >> 6;             // 0..15 (wave-uniform)
    #pragma unroll 1
    for (int cc = 0; cc < 2; ++cc) {
        const int c = cp + cc * 16;      // wave-uniform -> scalar weight loads
        const float* xc = x + ((size_t)n * C + c) * SP;

        const float wz0 = w0z[c*3+0], wz1 = w0z[c*3+1], wz2 = w0z[c*3+2];
        const float wx0 = w0x[c*3+0], wx1 = w0x[c*3+1], wx2 = w0x[c*3+2];
        const float wy0 = w0y[c*3+0], wy1 = w0y[c*3+1], wy2 = w0y[c*3+2];
        const float bz = b0z[c], bx = b0x[c], by = b0y[c], bs = bsz[c];
        float wsk[5];
        #pragma unroll
        for (int k = 0; k < 5; ++k) wsk[k] = wsz[c*5+k];

        // z-conv + h-conv
        float acc2[D];
        #pragma unroll
        for (int d = 0; d < D; ++d) acc2[d] = bx;

        #pragma unroll
        for (int dx = 0; dx < 3; ++dx) {
            const int hgg = hg + dx - 1;
            if (hgg < 0 || hgg >= H) continue;   // zero-pad: term (incl. bz) drops
            const float wxk = (dx == 0) ? wx0 : ((dx == 1) ? wx1 : wx2);

            float xcol[D];
            #pragma unroll
            for (int d = 0; d < D; ++d) xcol[d] = xc[(d * H + hgg) * W + w];

            #pragma unroll
            for (int d = 0; d < D; ++d) {
                float t = bz;
                if (d > 0)     t += wz0 * xcol[d - 1];
                t += wz1 * xcol[d];
                if (d < D - 1) t += wz2 * xcol[d + 1];
                acc2[d] += wxk * t;
            }
        }

        // w-conv via shuffles (W == 64 == wavefront)
        const bool has_l = (w > 0), has_r = (w < W - 1);
        float acc3[D];
        #pragma unroll
        for (int d = 0; d < D; ++d) {
            float left  = __shfl_up(acc2[d], 1);
            float right = __shfl_down(acc2[d], 1);
            float t = by + wy1 * acc2[d];
            if (has_l) t += wy0 * left;
            if (has_r) t += wy2 * right;
            acc3[d] = t;
        }

        // 3x 5-tap dilation-2 conv along D (pad 4), in registers
        #pragma unroll
        for (int it = 0; it < 3; ++it) {
            float s[D];
            #pragma unroll
            for (int d = 0; d < D; ++d) {
                float t = bs;
                #pragma unroll
                for (int k = 0; k < 5; ++k) {
                    int j = d + 2 * k - 4;
                    if (j >= 0 && j < D) t += wsk[k] * acc3[j];
                }
                s[d] = t;
            }
            #pragma unroll
            for (int d = 0; d < D; ++d) acc3[d] = s[d];
        }

        // pack pairs of d to bf16 and stash in LDS: smem[(c*16+dp)*64 + w]
        #pragma unroll
        for (int dp = 0; dp < D / 2; ++dp) {
            unsigned word = f2bf(acc3[2*dp]) | (f2bf(acc3[2*dp+1]) << 16);
            smem[(c * (D/2) + dp) * W + w] = word;
        }
    }

    __syncthreads();

    // ---------------- Phase B: pointwise mix + residual --------------------
    const int dp = tid >> 6;             // 0..15 -> d0 = 2dp, d1 = 2dp+1
    float hv0[C], hv1[C];
    #pragma unroll
    for (int ci = 0; ci < C; ++ci) {
        unsigned v = smem[(ci * (D/2) + dp) * W + w];
        hv0[ci] = bf_lo(v);
        hv1[ci] = bf_hi(v);
    }

    const size_t sp0 = (size_t)(2*dp) * H * W + (size_t)hg * W + w;  // d0 plane
    const size_t nbase = (size_t)n * C * SP;

    for (int co = 0; co < C; ++co) {
        float y0 = bp[co], y1 = bp[co];
        #pragma unroll
        for (int ci = 0; ci < C; ++ci) {
            const float wv = wp[co * C + ci];
            y0 += wv * hv0[ci];
            y1 += wv * hv1[ci];
        }
        const size_t i0 = nbase + (size_t)co * SP + sp0;
        const size_t i1 = i0 + (size_t)H * W;
        out[i0] = x[i0] * y0;
        out[i1] = x[i1] * y1;
    }
}

extern "C" void kernel_launch(void* const* d_in, const int* in_sizes, int n_in,
                              void* d_out, int out_size, void* d_ws, size_t ws_size,
                              hipStream_t stream)
{
    const float* x   = (const float*)d_in[0];
    const float* w0z = (const float*)d_in[1];
    const float* b0z = (const float*)d_in[2];
    const float* w0x = (const float*)d_in[3];
    const float* b0x = (const float*)d_in[4];
    const float* w0y = (const float*)d_in[5];
    const float* b0y = (const float*)d_in[6];
    const float* wsz = (const float*)d_in[7];
    const float* bsz = (const float*)d_in[8];
    const float* wp  = (const float*)d_in[9];
    const float* bp  = (const float*)d_in[10];
    float* out = (float*)d_out;

    const int grid = NT * H;             // 512 blocks, 1024 threads each
    lska_fused<<<grid, 1024, LDS_BYTES, stream>>>(
        x, w0z, b0z, w0x, b0x, w0y, b0y, wsz, bsz, wp, bp, out);
}

// Round 4
// 114.000 us; speedup vs baseline: 1.4818x; 1.4818x over previous
//
#include <hip/hip_runtime.h>

// Problem constants: x [B=1,T=8,C=32,D=32,H=64,W=64] fp32
constexpr int NT = 8;    // B*T
constexpr int C  = 32;
constexpr int D  = 32;
constexpr int H  = 64;
constexpr int W  = 64;   // == wavefront size: W-conv via lane shuffles
constexpr int ROWS = 4;  // h rows per block (one per wave)
constexpr int SP = D * H * W;       // per-channel spatial size = 131072
constexpr int HW = H * W;           // d-plane stride = 4096

// ---------------------------------------------------------------------------
// Kernel A: fused depthwise chain, LDS-free, MLP-optimized.
//   h = zconv3(x)+bz ; h = hconv3(h)+bx ; h = wconv3(h)+by ; 3x: h = zconv5_dil2(h)+bs
// One wave per (n,c,h) row; lane = w; thread owns full D=32 column in regs.
//
// Latency fix vs round 2: ALL 96 input loads (3 h-rows x 32 d) are issued
// up front into register arrays, fenced from the compute by
// sched_barrier(0), so ~96 loads/wave are in flight instead of ~3.
// Boundary h-rows use clamped addresses + zeroed tap weight: the term enters
// as wxk*(zconv+bz), so wxk=0 reproduces zero-pad drop semantics exactly.
//
// Algebraic fold: hconv and zconv commute (separable stencil);
//   h2[d] = bx + bz*sum(wxk) + zconv(hrow)[d],  hrow = sum_r wxk_r * x_r
// halves phase-1 FMA count.
// ---------------------------------------------------------------------------
__global__ __launch_bounds__(256, 3)
void dw_chain(const float* __restrict__ x,
              const float* __restrict__ w0z, const float* __restrict__ b0z,
              const float* __restrict__ w0x, const float* __restrict__ b0x,
              const float* __restrict__ w0y, const float* __restrict__ b0y,
              const float* __restrict__ wsz, const float* __restrict__ bsz,
              float* __restrict__ hdw)
{
    // XCD-chunk swizzle: 4096 blocks, 8 XCDs, chunk = 512. XCD k gets
    // lid in [k*512,(k+1)*512) == exactly one n (all c, all htile):
    // halo-row re-reads stay in that XCD's L2.
    const int rr  = blockIdx.x;
    const int lid = (rr & 7) * (NT * C * (H / ROWS) / 8) + (rr >> 3);
    const int htile = lid % (H / ROWS);
    const int c     = (lid / (H / ROWS)) % C;
    const int n     = lid / ((H / ROWS) * C);

    const int tid = threadIdx.x;
    const int w   = tid & 63;                  // lane
    const int hg  = htile * ROWS + (tid >> 6); // h row (wave-uniform)

    const float* xc = x + ((size_t)n * C + c) * SP;

    // Per-channel weights (block-uniform -> scalar regs)
    const float wz0 = w0z[c*3+0], wz1 = w0z[c*3+1], wz2 = w0z[c*3+2];
    const float wx1 = w0x[c*3+1];
    const float wy0 = w0y[c*3+0], wy1 = w0y[c*3+1], wy2 = w0y[c*3+2];
    const float bz = b0z[c], bx = b0x[c], by = b0y[c], bs = bsz[c];
    float wsk[5];
    #pragma unroll
    for (int k = 0; k < 5; ++k) wsk[k] = wsz[c*5+k];

    // Boundary handling: clamp row index (load stays legal), zero the weight.
    const float wxk0 = (hg > 0)     ? w0x[c*3+0] : 0.f;
    const float wxk2 = (hg < H - 1) ? w0x[c*3+2] : 0.f;
    const int   hm = (hg > 0)     ? hg - 1 : 0;
    const int   hp = (hg < H - 1) ? hg + 1 : H - 1;

    // ---- Issue ALL 96 loads (3 rows x full D column) --------------------
    const float* p0 = xc + (size_t)hm * W + w;
    const float* p1 = xc + (size_t)hg * W + w;
    const float* p2 = xc + (size_t)hp * W + w;
    float a0[D], a1[D], a2[D];
    #pragma unroll
    for (int d = 0; d < D; ++d) {
        a0[d] = p0[(size_t)d * HW];
        a1[d] = p1[(size_t)d * HW];
        a2[d] = p2[(size_t)d * HW];
    }
    __builtin_amdgcn_sched_barrier(0);   // keep loads batched ahead of compute

    // ---- h-conv (along H) first: hrow = wxk0*r0 + wx1*r1 + wxk2*r2 ------
    float hrow[D];
    #pragma unroll
    for (int d = 0; d < D; ++d)
        hrow[d] = wxk0 * a0[d] + wx1 * a1[d] + wxk2 * a2[d];

    // ---- z-conv (along D) + folded biases --------------------------------
    const float cb = bx + (wxk0 + wx1 + wxk2) * bz;
    float acc2[D];
    #pragma unroll
    for (int d = 0; d < D; ++d) {
        float t = cb + wz1 * hrow[d];
        if (d > 0)     t += wz0 * hrow[d - 1];
        if (d < D - 1) t += wz2 * hrow[d + 1];
        acc2[d] = t;
    }

    // ---- w-conv via lane shuffles (W == 64 == wavefront) -----------------
    const bool has_l = (w > 0), has_r = (w < W - 1);
    float acc3[D];
    #pragma unroll
    for (int d = 0; d < D; ++d) {
        float left  = __shfl_up(acc2[d], 1);
        float right = __shfl_down(acc2[d], 1);
        float t = by + wy1 * acc2[d];
        if (has_l) t += wy0 * left;
        if (has_r) t += wy2 * right;
        acc3[d] = t;
    }

    // ---- three 5-tap dilation-2 convs along D (pad 4), in registers ------
    #pragma unroll
    for (int it = 0; it < 3; ++it) {
        float s[D];
        #pragma unroll
        for (int d = 0; d < D; ++d) {
            float t = bs;
            #pragma unroll
            for (int k = 0; k < 5; ++k) {
                int j = d + 2 * k - 4;
                if (j >= 0 && j < D) t += wsk[k] * acc3[j];
            }
            s[d] = t;
        }
        #pragma unroll
        for (int d = 0; d < D; ++d) acc3[d] = s[d];
    }

    // ---- store column (coalesced across lanes per d) ---------------------
    float* oc = hdw + ((size_t)n * C + c) * SP + (size_t)hg * W + w;
    #pragma unroll
    for (int d = 0; d < D; ++d) oc[(size_t)d * HW] = acc3[d];
}

// ---------------------------------------------------------------------------
// Kernel B: pointwise 1x1x1 conv over channels + residual multiply, IN PLACE
// on io (= d_out holding the depthwise-chain result). At BW roofline.
// ---------------------------------------------------------------------------
__global__ __launch_bounds__(256)
void pw_mul(const float* __restrict__ x,
            const float* __restrict__ wp, const float* __restrict__ bp,
            float* __restrict__ io)
{
    const size_t p = (size_t)blockIdx.x * 256 + threadIdx.x;  // (n, d, h, w)
    const size_t n  = p / SP;
    const size_t sp = p % SP;
    const size_t base = n * (size_t)C * SP + sp;

    float v[C];
    #pragma unroll
    for (int ci = 0; ci < C; ++ci) v[ci] = io[base + (size_t)ci * SP];

    for (int co = 0; co < C; ++co) {
        float y = bp[co];
        #pragma unroll
        for (int ci = 0; ci < C; ++ci) y += wp[co * C + ci] * v[ci];
        const size_t idx = base + (size_t)co * SP;
        io[idx] = x[idx] * y;
    }
}

extern "C" void kernel_launch(void* const* d_in, const int* in_sizes, int n_in,
                              void* d_out, int out_size, void* d_ws, size_t ws_size,
                              hipStream_t stream)
{
    const float* x   = (const float*)d_in[0];
    const float* w0z = (const float*)d_in[1];
    const float* b0z = (const float*)d_in[2];
    const float* w0x = (const float*)d_in[3];
    const float* b0x = (const float*)d_in[4];
    const float* w0y = (const float*)d_in[5];
    const float* b0y = (const float*)d_in[6];
    const float* wsz = (const float*)d_in[7];
    const float* bsz = (const float*)d_in[8];
    const float* wp  = (const float*)d_in[9];
    const float* bp  = (const float*)d_in[10];
    float* out = (float*)d_out;

    // Kernel A: depthwise chain -> d_out (scratch)
    const int gridA = NT * C * (H / ROWS);        // 4096 blocks, 256 thr
    dw_chain<<<gridA, 256, 0, stream>>>(x, w0z, b0z, w0x, b0x, w0y, b0y,
                                        wsz, bsz, out);

    // Kernel B: pointwise + residual, in place on d_out
    const int positions = NT * SP;                // 1,048,576
    pw_mul<<<positions / 256, 256, 0, stream>>>(x, wp, bp, out);
}